// Round 2
// baseline (849.902 us; speedup 1.0000x reference)
//
#include <hip/hip_runtime.h>
#include <hip/hip_bf16.h>

#define DD 64

// ---- degree histogram over dst ----
__global__ __launch_bounds__(256) void deg_kernel(const int* __restrict__ dst,
                                                  float* __restrict__ deg, int E) {
    int e = blockIdx.x * blockDim.x + threadIdx.x;
    if (e < E) atomicAdd(&deg[dst[e]], 1.0f);
}

__global__ __launch_bounds__(256) void inv_kernel(const float* __restrict__ deg,
                                                  float* __restrict__ inv, int n) {
    int i = blockIdx.x * blockDim.x + threadIdx.x;
    if (i < n) inv[i] = rsqrtf(deg[i] + 1.0f);
}

// ---- [nrows,64] @ [64,64] -> f32. W staged in LDS, 4 rows/block. ----
__global__ __launch_bounds__(256) void gemm64(const float* __restrict__ X,
                                              const float* __restrict__ W,
                                              float* __restrict__ Y, int nrows) {
    __shared__ float Ws[DD * DD];
    __shared__ float Xs[4 * DD];
    int tid = threadIdx.x;
    int tx = tid & 63, ty = tid >> 6;
    for (int i = tid; i < DD * DD; i += 256) Ws[i] = W[i];
    int row = blockIdx.x * 4 + ty;
    if (row < nrows) Xs[tid] = X[row * DD + tx];
    __syncthreads();
    if (row < nrows) {
        float acc = 0.f;
#pragma unroll
        for (int k = 0; k < DD; ++k) acc = fmaf(Xs[ty * DD + k], Ws[k * DD + tx], acc);
        Y[row * DD + tx] = acc;
    }
}

// ---- edge scatter: one wave per edge, lane = feature dim ----
__global__ __launch_bounds__(256) void scatter_kernel(const int* __restrict__ src,
                                                      const int* __restrict__ dst,
                                                      const float* __restrict__ inv,
                                                      const float* __restrict__ XW,
                                                      float* __restrict__ AGG, int E) {
    int idx = blockIdx.x * blockDim.x + threadIdx.x;
    int e = idx >> 6, lane = idx & 63;
    if (e < E) {
        int s = src[e], d = dst[e];
        float c = inv[s] * inv[d];
        atomicAdd(&AGG[d * DD + lane], XW[s * DD + lane] * c);
    }
}

// ---- self-loop + bias (+ relu) ----
__global__ __launch_bounds__(256) void bias_act_kernel(float* __restrict__ AGG,
                                                       const float* __restrict__ XW,
                                                       const float* __restrict__ inv,
                                                       const float* __restrict__ b,
                                                       int n, int do_relu) {
    int idx = blockIdx.x * blockDim.x + threadIdx.x;
    if (idx < n * DD) {
        int i = idx >> 6, d = idx & 63;
        float iv = inv[i];
        float v = AGG[idx] + XW[idx] * iv * iv + b[d];
        AGG[idx] = do_relu ? fmaxf(v, 0.f) : v;
    }
}

// ---- log_softmax over 64 features: one wave per row (in-place safe) ----
__global__ __launch_bounds__(256) void logsoftmax_kernel(float* __restrict__ Z, int n) {
    int idx = blockIdx.x * blockDim.x + threadIdx.x;
    int row = idx >> 6, lane = idx & 63;
    if (row < n) {
        float v = Z[row * DD + lane];
        float m = v;
#pragma unroll
        for (int o = 32; o > 0; o >>= 1) m = fmaxf(m, __shfl_xor(m, o, 64));
        float ex = __expf(v - m);
        float s = ex;
#pragma unroll
        for (int o = 32; o > 0; o >>= 1) s += __shfl_xor(s, o, 64);
        Z[row * DD + lane] = v - m - __logf(s);
    }
}

extern "C" void kernel_launch(void* const* d_in, const int* in_sizes, int n_in,
                              void* d_out, int out_size, void* d_ws, size_t ws_size,
                              hipStream_t stream) {
    const float* x  = (const float*)d_in[0];
    const int*   ei = (const int*)d_in[1];
    const float* W1 = (const float*)d_in[2];
    const float* b1 = (const float*)d_in[3];
    const float* W2 = (const float*)d_in[4];
    const float* b2 = (const float*)d_in[5];
    float* out = (float*)d_out;

    const int n = in_sizes[0] / DD;
    const int E = in_sizes[1] / 2;
    const int* src = ei;
    const int* dst = ei + E;

    float* ws   = (float*)d_ws;
    float* deg  = ws;
    float* inv  = deg + n;
    float* bufA = inv + n;                    // xw (layer1), then hw (layer2)
    float* bufB = bufA + (size_t)n * DD;      // agg1 -> h
    // layer-2 aggregation goes directly into d_out; logsoftmax is in-place.

    hipMemsetAsync(deg, 0, (size_t)n * sizeof(float), stream);
    hipMemsetAsync(bufB, 0, (size_t)n * DD * sizeof(float), stream);
    hipMemsetAsync(out, 0, (size_t)n * DD * sizeof(float), stream);

    deg_kernel<<<(E + 255) / 256, 256, 0, stream>>>(dst, deg, E);
    inv_kernel<<<(n + 255) / 256, 256, 0, stream>>>(deg, inv, n);

    // layer 1
    gemm64<<<(n + 3) / 4, 256, 0, stream>>>(x, W1, bufA, n);
    scatter_kernel<<<((size_t)E * 64 + 255) / 256, 256, 0, stream>>>(src, dst, inv, bufA, bufB, E);
    bias_act_kernel<<<(n * DD + 255) / 256, 256, 0, stream>>>(bufB, bufA, inv, b1, n, 1);

    // layer 2
    gemm64<<<(n + 3) / 4, 256, 0, stream>>>(bufB, W2, bufA, n);
    scatter_kernel<<<((size_t)E * 64 + 255) / 256, 256, 0, stream>>>(src, dst, inv, bufA, out, E);
    bias_act_kernel<<<(n * DD + 255) / 256, 256, 0, stream>>>(out, bufA, inv, b2, n, 0);

    logsoftmax_kernel<<<(n * DD + 255) / 256, 256, 0, stream>>>(out, n);
}

// Round 3
// 492.858 us; speedup vs baseline: 1.7244x; 1.7244x over previous
//
#include <hip/hip_runtime.h>

#define DD 64

// ================= CSR build =================
__global__ __launch_bounds__(256) void deg_int_kernel(const int* __restrict__ dst,
                                                      int* __restrict__ degi, int E) {
    int e = blockIdx.x * blockDim.x + threadIdx.x;
    if (e < E) atomicAdd(&degi[dst[e]], 1);
}

__global__ __launch_bounds__(256) void scan1_kernel(const int* __restrict__ degi,
                                                    int* __restrict__ rowptr,
                                                    int* __restrict__ bsum, int n) {
    __shared__ int s[256];
    int tid = threadIdx.x;
    int i = blockIdx.x * 256 + tid;
    int v = (i < n) ? degi[i] : 0;
    s[tid] = v;
    __syncthreads();
    for (int o = 1; o < 256; o <<= 1) {
        int t = (tid >= o) ? s[tid - o] : 0;
        __syncthreads();
        s[tid] += t;
        __syncthreads();
    }
    if (i < n) rowptr[i] = s[tid] - v;  // exclusive within block
    if (tid == 255) bsum[blockIdx.x] = s[255];
}

__global__ __launch_bounds__(1024) void scan2_kernel(int* __restrict__ bsum, int nb) {
    __shared__ int s[1024];
    int tid = threadIdx.x;
    int v = (tid < nb) ? bsum[tid] : 0;
    s[tid] = v;
    __syncthreads();
    for (int o = 1; o < 1024; o <<= 1) {
        int t = (tid >= o) ? s[tid - o] : 0;
        __syncthreads();
        s[tid] += t;
        __syncthreads();
    }
    if (tid < nb) bsum[tid] = s[tid] - v;  // exclusive block offsets
}

__global__ __launch_bounds__(256) void scan3_kernel(int* __restrict__ rowptr,
                                                    int* __restrict__ cursor,
                                                    float* __restrict__ inv,
                                                    const int* __restrict__ degi,
                                                    const int* __restrict__ bsum,
                                                    int n, int E) {
    int i = blockIdx.x * 256 + threadIdx.x;
    if (i < n) {
        int r = rowptr[i] + bsum[blockIdx.x];
        rowptr[i] = r;
        cursor[i] = r;
        inv[i] = rsqrtf((float)degi[i] + 1.0f);
    }
    if (i == 0) rowptr[n] = E;
}

__global__ __launch_bounds__(256) void place_kernel(const int* __restrict__ src,
                                                    const int* __restrict__ dst,
                                                    const float* __restrict__ inv,
                                                    int* __restrict__ cursor,
                                                    int* __restrict__ srcs,
                                                    float* __restrict__ coefs, int E) {
    int e = blockIdx.x * blockDim.x + threadIdx.x;
    if (e < E) {
        int s = src[e], d = dst[e];
        int pos = atomicAdd(&cursor[d], 1);
        srcs[pos] = s;
        coefs[pos] = inv[s] * inv[d];
    }
}

// ================= GEMM: [nrows,64] @ [64,64], W column in VGPRs =================
__global__ __launch_bounds__(256) void gemm64_reg(const float* __restrict__ X,
                                                  const float* __restrict__ W,
                                                  float* __restrict__ Y, int nrows) {
    __shared__ float Ws[DD * DD];
    int tid = threadIdx.x;
    int tx = tid & 63;
    for (int i = tid; i < DD * DD; i += 256) Ws[i] = W[i];  // coalesced stage
    __syncthreads();
    float wreg[DD];
#pragma unroll
    for (int k = 0; k < DD; ++k) wreg[k] = Ws[k * DD + tx];  // lane tx holds column tx

    int nwaves = (gridDim.x * 256) >> 6;
    int wave = (blockIdx.x * 256 + tid) >> 6;
    wave = __builtin_amdgcn_readfirstlane(wave);  // force wave-uniform (scalar) row index
    for (int row = wave; row < nrows; row += nwaves) {
        const float* xr = X + (size_t)row * DD;  // uniform address -> scalar loads
        float acc = 0.f;
#pragma unroll
        for (int k = 0; k < DD; ++k) acc = fmaf(xr[k], wreg[k], acc);
        Y[(size_t)row * DD + tx] = acc;
    }
}

// ================= fused aggregation: one wave per node =================
// MODE 0: self-loop + bias + relu.  MODE 1: self-loop + bias + log_softmax.
template <int MODE>
__global__ __launch_bounds__(256) void agg_kernel(const int* __restrict__ rowptr,
                                                  const int* __restrict__ srcs,
                                                  const float* __restrict__ coefs,
                                                  const float* __restrict__ inv,
                                                  const float* __restrict__ XW,
                                                  const float* __restrict__ b,
                                                  float* __restrict__ OUT, int n) {
    int gid = blockIdx.x * 256 + threadIdx.x;
    int i = gid >> 6, lane = gid & 63;
    if (i >= n) return;
    float iv = inv[i];
    float acc = XW[(size_t)i * DD + lane] * (iv * iv) + b[lane];
    float acc2 = 0.f;
    int j = rowptr[i], jend = rowptr[i + 1];
    for (; j + 1 < jend; j += 2) {  // 2-way unroll for memory-level parallelism
        int sa = srcs[j], sb = srcs[j + 1];
        float ca = coefs[j], cb = coefs[j + 1];
        float va = XW[(size_t)sa * DD + lane];
        float vb = XW[(size_t)sb * DD + lane];
        acc = fmaf(va, ca, acc);
        acc2 = fmaf(vb, cb, acc2);
    }
    if (j < jend) acc = fmaf(XW[(size_t)srcs[j] * DD + lane], coefs[j], acc);
    acc += acc2;
    if (MODE == 0) {
        OUT[(size_t)i * DD + lane] = fmaxf(acc, 0.f);
    } else {
        float m = acc;
#pragma unroll
        for (int o = 32; o > 0; o >>= 1) m = fmaxf(m, __shfl_xor(m, o, 64));
        float ex = __expf(acc - m);
        float ssum = ex;
#pragma unroll
        for (int o = 32; o > 0; o >>= 1) ssum += __shfl_xor(ssum, o, 64);
        OUT[(size_t)i * DD + lane] = acc - m - __logf(ssum);
    }
}

extern "C" void kernel_launch(void* const* d_in, const int* in_sizes, int n_in,
                              void* d_out, int out_size, void* d_ws, size_t ws_size,
                              hipStream_t stream) {
    const float* x  = (const float*)d_in[0];
    const int*   ei = (const int*)d_in[1];
    const float* W1 = (const float*)d_in[2];
    const float* b1 = (const float*)d_in[3];
    const float* W2 = (const float*)d_in[4];
    const float* b2 = (const float*)d_in[5];
    float* out = (float*)d_out;

    const int n = in_sizes[0] / DD;
    const int E = in_sizes[1] / 2;
    const int* src = ei;
    const int* dst = ei + E;

    // workspace layout (all 4-byte elements)
    int*   degi   = (int*)d_ws;
    int*   rowptr = degi + n;          // n+1
    int*   cursor = rowptr + (n + 1);  // n
    int*   bsum   = cursor + n;        // 1024
    int*   srcs   = bsum + 1024;       // E
    float* coefs  = (float*)(srcs + E);  // E
    float* inv    = coefs + E;           // n
    float* bufA   = inv + n;             // n*64
    float* bufB   = bufA + (size_t)n * DD;  // n*64

    const int nb = (n + 255) / 256;

    hipMemsetAsync(degi, 0, (size_t)n * sizeof(int), stream);
    deg_int_kernel<<<(E + 255) / 256, 256, 0, stream>>>(dst, degi, E);
    scan1_kernel<<<nb, 256, 0, stream>>>(degi, rowptr, bsum, n);
    scan2_kernel<<<1, 1024, 0, stream>>>(bsum, nb);
    scan3_kernel<<<nb, 256, 0, stream>>>(rowptr, cursor, inv, degi, bsum, n, E);
    place_kernel<<<(E + 255) / 256, 256, 0, stream>>>(src, dst, inv, cursor, srcs, coefs, E);

    // layer 1: xw = x@W1 ; h = relu(agg + selfloop + b1)
    gemm64_reg<<<512, 256, 0, stream>>>(x, W1, bufA, n);
    agg_kernel<0><<<(n * DD + 255) / 256, 256, 0, stream>>>(rowptr, srcs, coefs, inv, bufA, b1, bufB, n);

    // layer 2: hw = h@W2 ; out = log_softmax(agg + selfloop + b2)
    gemm64_reg<<<512, 256, 0, stream>>>(bufB, W2, bufA, n);
    agg_kernel<1><<<(n * DD + 255) / 256, 256, 0, stream>>>(rowptr, srcs, coefs, inv, bufA, b2, out, n);
}